// Round 4
// baseline (192.733 us; speedup 1.0000x reference)
//
#include <hip/hip_runtime.h>

#define T_DATA 20000
#define S_NO   128
#define T_HIST 100
#define J_PAD  104              // conv taps padded to 13 chunks of 8 (zeros past 99)
#define NELEM  (T_DATA * S_NO)  // 2,560,000

__device__ __forceinline__ float sigm(float v) {
    return 1.0f / (1.0f + __expf(-v));
}

__device__ __forceinline__ void fma4(float4& a, float s, const float4 c) {
    a.x = fmaf(s, c.x, a.x); a.y = fmaf(s, c.y, a.y);
    a.z = fmaf(s, c.z, a.z); a.w = fmaf(s, c.w, a.w);
}

// ---------------------------------------------------------------------------
// K1: prep (17 blocks).
//  blocks 0..15: transpose C -> Ct[k][s]
//  block 16:     ancestor kernel transposed [j][s], j zero-padded to 104;
//                history kernel [s][j]; flag = any(K_hist != 0)
// ---------------------------------------------------------------------------
__global__ void __launch_bounds__(256) k1_prep(const float* __restrict__ C,
                        const float* __restrict__ K_spike,
                        const float* __restrict__ tau_spike,
                        const float* __restrict__ delta_spike,
                        const float* __restrict__ tau_hist,
                        const float* __restrict__ K_hist,
                        const float* __restrict__ delta_hist,
                        float* __restrict__ Ct,
                        float* __restrict__ anc_kT,
                        float* __restrict__ hist_k,
                        int* __restrict__ flag) {
    const int tid = threadIdx.x;
    const int b   = blockIdx.x;
    if (b < 16) {
#pragma unroll
        for (int i = 0; i < 4; ++i) {
            const int q = b * 1024 + i * 256 + tid;   // q = s*128 + k
            Ct[(q & 127) * S_NO + (q >> 7)] = C[q];
        }
        return;
    }
    const int s    = tid & 127;
    const int half = tid >> 7;            // 0/1 -> j chunks of 52
    {   // ancestor kernel transposed, padded: anc_kT[j*128 + s], j in [0,104)
        float d  = delta_spike[s];
        float i0 = __expf(-tau_spike[0]);
        float i1 = __expf(-tau_spike[1]);
        float i2 = __expf(-tau_spike[2]);
        float k0 = K_spike[s * 3 + 0], k1 = K_spike[s * 3 + 1], k2 = K_spike[s * 3 + 2];
        for (int j = half * 52; j < half * 52 + 52; ++j) {
            float v = 0.0f;
            if (j < T_HIST) {
                float t  = fmaxf((float)j - d, 0.0f);
                float x0 = t * i0, x1 = t * i1, x2 = t * i2;
                v = k0 * x0 * __expf(-x0) + k1 * x1 * __expf(-x1) + k2 * x2 * __expf(-x2);
            }
            anc_kT[j * S_NO + s] = v;
        }
    }
    {   // history kernel per-subunit: hist_k[s*100 + j]
        float d  = delta_hist[s];
        float i0 = __expf(-tau_hist[0]);
        float i1 = __expf(-tau_hist[1]);
        float i2 = __expf(-tau_hist[2]);
        float k0 = K_hist[s * 3 + 0], k1 = K_hist[s * 3 + 1], k2 = K_hist[s * 3 + 2];
        for (int j = half * 50; j < half * 50 + 50; ++j) {
            float t  = fmaxf((float)j - d, 0.0f);
            float x0 = t * i0, x1 = t * i1, x2 = t * i2;
            hist_k[s * T_HIST + j] =
                k0 * x0 * __expf(-x0) + k1 * x1 * __expf(-x1) + k2 * x2 * __expf(-x2);
        }
    }
    if (tid == 0) *flag = 0;
    __syncthreads();
    if (tid < 128) {
        if (K_hist[s * 3] != 0.0f || K_hist[s * 3 + 1] != 0.0f || K_hist[s * 3 + 2] != 0.0f)
            atomicOr(flag, 1);
    }
}

// ---------------------------------------------------------------------------
// K2: dual GEMM  A = Z @ C^T (-> ws), R = Y @ C^T (-> out1)
// Block: 32 t x 128 s, 256 threads. Thread: 2t x 8s for both outputs.
// Per k4-step: 4 LDS b128 serve 128 FMAs (32:1); c amortized over 2 t.
// ---------------------------------------------------------------------------
__global__ void __launch_bounds__(256) k2_gemm(const float* __restrict__ Z,
                                               const float* __restrict__ Y,
                                               const float* __restrict__ Ct,
                                               float* __restrict__ A,
                                               float* __restrict__ R) {
    __shared__ float Zt[32 * 128];
    __shared__ float Yt[32 * 128];
    const int t0  = blockIdx.x * 32;
    const int tid = threadIdx.x;
    {
        const float4* Zg = (const float4*)(Z + t0 * S_NO);
        const float4* Yg = (const float4*)(Y + t0 * S_NO);
        float4* Zl = (float4*)Zt;
        float4* Yl = (float4*)Yt;
        for (int q = tid; q < 1024; q += 256) { Zl[q] = Zg[q]; Yl[q] = Yg[q]; }
    }
    __syncthreads();
    const int sg = tid & 15;          // s0 = sg*8
    const int tg = tid >> 4;          // 0..15 -> local t = tg*2 + i
    const int s0 = sg * 8;
    float4 accA[2][2] = {{{0,0,0,0},{0,0,0,0}},{{0,0,0,0},{0,0,0,0}}};
    float4 accR[2][2] = {{{0,0,0,0},{0,0,0,0}},{{0,0,0,0},{0,0,0,0}}};
    for (int k4 = 0; k4 < 32; ++k4) {
        float4 c[4][2];
#pragma unroll
        for (int k = 0; k < 4; ++k) {
            c[k][0] = *(const float4*)&Ct[(k4 * 4 + k) * S_NO + s0];
            c[k][1] = *(const float4*)&Ct[(k4 * 4 + k) * S_NO + s0 + 4];
        }
#pragma unroll
        for (int i = 0; i < 2; ++i) {
            const float4 z = *(const float4*)&Zt[(tg * 2 + i) * S_NO + k4 * 4];
            fma4(accA[i][0], z.x, c[0][0]); fma4(accA[i][1], z.x, c[0][1]);
            fma4(accA[i][0], z.y, c[1][0]); fma4(accA[i][1], z.y, c[1][1]);
            fma4(accA[i][0], z.z, c[2][0]); fma4(accA[i][1], z.z, c[2][1]);
            fma4(accA[i][0], z.w, c[3][0]); fma4(accA[i][1], z.w, c[3][1]);
            const float4 y = *(const float4*)&Yt[(tg * 2 + i) * S_NO + k4 * 4];
            fma4(accR[i][0], y.x, c[0][0]); fma4(accR[i][1], y.x, c[0][1]);
            fma4(accR[i][0], y.y, c[1][0]); fma4(accR[i][1], y.y, c[1][1]);
            fma4(accR[i][0], y.z, c[2][0]); fma4(accR[i][1], y.z, c[2][1]);
            fma4(accR[i][0], y.w, c[3][0]); fma4(accR[i][1], y.w, c[3][1]);
        }
    }
#pragma unroll
    for (int i = 0; i < 2; ++i) {
        const int row = (t0 + tg * 2 + i) * S_NO + s0;
        *(float4*)&A[row]     = accA[i][0];
        *(float4*)&A[row + 4] = accA[i][1];
        *(float4*)&R[row]     = accR[i][0];
        *(float4*)&R[row + 4] = accR[i][1];
    }
}

// ---------------------------------------------------------------------------
// K3: fused 100-tap causal conv + final map. No LDS, no barrier.
// Thread: one s, 8 t's. Conv in 13 chunks of 8 taps with a 15-deep register
// window (all indices static). Taps zero-padded to 104 rows.
// Grid: 1250 blocks (5000 waves -> ~61% occupancy cap).
// ---------------------------------------------------------------------------
template <bool GUARD>
__device__ __forceinline__ void conv8(const float* __restrict__ A,
                                      const float* __restrict__ kT,
                                      int t0, int s, float acc[8]) {
    for (int c = 0; c < 13; ++c) {
        const int B = t0 - 8 * c - 8;       // window base row
        float w[15];
        float kj[8];
#pragma unroll
        for (int q = 0; q < 15; ++q) {
            const int u = B + q;
            if (GUARD)
                w[q] = (u >= 0) ? A[u * S_NO + s] : 0.0f;
            else
                w[q] = A[u * S_NO + s];
        }
#pragma unroll
        for (int r = 0; r < 8; ++r) kj[r] = kT[(8 * c + r) * S_NO + s];
#pragma unroll
        for (int r = 0; r < 8; ++r)
#pragma unroll
            for (int i = 0; i < 8; ++i)
                acc[i] = fmaf(kj[r], w[i + 7 - r], acc[i]);   // row = t0+i-1-(8c+r)
    }
}

__global__ void __launch_bounds__(256) k3_fused(const float* __restrict__ A,
                                                const float* __restrict__ anc_kT,
                                                const float* __restrict__ S_conv,
                                                const float* __restrict__ noise,
                                                const float* __restrict__ W_sub,
                                                const float* __restrict__ theta_syn,
                                                const float* __restrict__ theta_spike,
                                                const float* __restrict__ W_spike,
                                                const int* __restrict__ flag,
                                                float* __restrict__ out0,
                                                float* __restrict__ out1,
                                                float* __restrict__ out2,
                                                float* __restrict__ out3,
                                                float* __restrict__ Fws) {
    const int tid = threadIdx.x;
    const int s   = tid & 127;
    const int tg  = tid >> 7;                       // wave-uniform (0/1)
    const int t0  = blockIdx.x * 16 + tg * 8;
    float acc[8] = {0,0,0,0,0,0,0,0};
    if (t0 >= J_PAD) conv8<false>(A, anc_kT, t0, s, acc);
    else             conv8<true >(A, anc_kT, t0, s, acc);

    if (*flag == 0) {
        const float tsy = theta_syn[s], wsub = W_sub[s];
        const float wsp = W_spike[s],  tsp  = theta_spike[s];
#pragma unroll
        for (int i = 0; i < 8; ++i) {
            const int n = (t0 + i) * S_NO + s;
            const float x  = sigm(S_conv[n] + tsy + out1[n] + acc[i]);
            const float dn = fmaf(x, wsp, tsp);
            const float z  = sigm(dn + noise[n]);
            out0[n] = x * wsub;
            out1[n] = z;
            out2[n] = dn;
            out3[n] = dn;
        }
    } else {
#pragma unroll
        for (int i = 0; i < 8; ++i) Fws[(t0 + i) * S_NO + s] = acc[i];
    }
}

// ---------------------------------------------------------------------------
// K4: exact sequential recurrence (only when hist kernel != 0).
// ---------------------------------------------------------------------------
__global__ void __launch_bounds__(64) k4_scan(const float* __restrict__ S_conv,
                                              const float* __restrict__ noise,
                                              const float* __restrict__ W_sub,
                                              const float* __restrict__ theta_syn,
                                              const float* __restrict__ theta_spike,
                                              const float* __restrict__ W_spike,
                                              const float* __restrict__ hist_k,
                                              const int* __restrict__ flag,
                                              const float* __restrict__ Fws,
                                              float* __restrict__ out0,
                                              float* __restrict__ out1,
                                              float* __restrict__ out2,
                                              float* __restrict__ out3) {
    if (*flag == 0) return;
    __shared__ float zr[128];
    const int s = blockIdx.x;
    const int l = threadIdx.x;
    zr[l] = 0.0f; zr[l + 64] = 0.0f;      // single wave: no barrier needed
    const float hk0 = (l < T_HIST) ? hist_k[s * T_HIST + l] : 0.0f;
    const float hk1 = (l + 64 < T_HIST) ? hist_k[s * T_HIST + l + 64] : 0.0f;
    const float tsy = theta_syn[s], wsub = W_sub[s];
    const float wsp = W_spike[s],  tsp  = theta_spike[s];
    for (int t = 0; t < T_DATA; ++t) {
        float fh = hk0 * zr[(t - 1 - l) & 127];
        fh = fmaf(hk1, zr[(t - 65 - l) & 127], fh);
#pragma unroll
        for (int m = 1; m < 64; m <<= 1) fh += __shfl_xor(fh, m, 64);
        const int n = t * S_NO + s;
        const float basev = S_conv[n] + tsy + out1[n] + Fws[n];
        const float x  = sigm(basev + fh);
        const float dn = fmaf(x, wsp, tsp);
        const float z  = sigm(dn + noise[n]);
        if (l == 0) {
            out0[n] = x * wsub;
            out1[n] = z;
            out2[n] = dn;
            out3[n] = dn;
            zr[t & 127] = z;
        }
    }
}

// ---------------------------------------------------------------------------
extern "C" void kernel_launch(void* const* d_in, const int* in_sizes, int n_in,
                              void* d_out, int out_size, void* d_ws, size_t ws_size,
                              hipStream_t stream) {
    const float* S_conv  = (const float*)d_in[0];
    const float* Y_anc   = (const float*)d_in[1];
    const float* Z_anc   = (const float*)d_in[2];
    const float* noise   = (const float*)d_in[3];
    const float* C_den   = (const float*)d_in[4];
    const float* W_sub   = (const float*)d_in[5];
    const float* th_syn  = (const float*)d_in[6];
    const float* K_spk   = (const float*)d_in[7];
    const float* tau_spk = (const float*)d_in[8];
    const float* dl_spk  = (const float*)d_in[9];
    const float* th_spk  = (const float*)d_in[10];
    const float* W_spk   = (const float*)d_in[11];
    const float* tau_h   = (const float*)d_in[12];
    const float* K_h     = (const float*)d_in[13];
    const float* dl_h    = (const float*)d_in[14];

    float* out  = (float*)d_out;
    float* out0 = out;
    float* out1 = out + NELEM;
    float* out2 = out + 2 * NELEM;
    float* out3 = out + 3 * NELEM;

    // workspace: A | F | Ct | anc_kT (104 rows) | hist_k | flag
    float* ws     = (float*)d_ws;
    float* wsA    = ws;
    float* wsF    = ws + NELEM;
    float* Ct     = ws + 2 * NELEM;
    float* anc_kT = Ct + S_NO * S_NO;
    float* hist_k = anc_kT + J_PAD * S_NO;
    int*   flag   = (int*)(hist_k + S_NO * T_HIST);

    k1_prep<<<17, 256, 0, stream>>>(C_den, K_spk, tau_spk, dl_spk, tau_h, K_h, dl_h,
                                    Ct, anc_kT, hist_k, flag);
    // A -> ws, R -> out1
    k2_gemm<<<T_DATA / 32, 256, 0, stream>>>(Z_anc, Y_anc, Ct, wsA, out1);
    // fused conv + final map (reads A from ws, R from out1)
    k3_fused<<<T_DATA / 16, 256, 0, stream>>>(wsA, anc_kT, S_conv, noise,
                                              W_sub, th_syn, th_spk, W_spk,
                                              flag, out0, out1, out2, out3, wsF);
    // exact sequential path (no-op when hist kernel is all-zero)
    k4_scan<<<S_NO, 64, 0, stream>>>(S_conv, noise, W_sub, th_syn, th_spk, W_spk,
                                     hist_k, flag, wsF, out0, out1, out2, out3);
}

// Round 6
// 170.931 us; speedup vs baseline: 1.1275x; 1.1275x over previous
//
#include <hip/hip_runtime.h>

#define T_DATA 20000
#define S_NO   128
#define T_HIST 100
#define J_PAD  104              // conv taps padded to 13 chunks of 8 (zeros past 99)
#define NELEM  (T_DATA * S_NO)  // 2,560,000

__device__ __forceinline__ float sigm(float v) {
    return 1.0f / (1.0f + __expf(-v));
}

__device__ __forceinline__ void fma4(float4& a, float s, const float4 c) {
    a.x = fmaf(s, c.x, a.x); a.y = fmaf(s, c.y, a.y);
    a.z = fmaf(s, c.z, a.z); a.w = fmaf(s, c.w, a.w);
}

// ---------------------------------------------------------------------------
// K1: prep (17 blocks).
//  blocks 0..15: transpose C -> Ct[k][s]
//  block 16:     ancestor kernel transposed [j][s], j zero-padded to 104;
//                history kernel [s][j]; flag = any(K_hist != 0)
// ---------------------------------------------------------------------------
__global__ void __launch_bounds__(256) k1_prep(const float* __restrict__ C,
                        const float* __restrict__ K_spike,
                        const float* __restrict__ tau_spike,
                        const float* __restrict__ delta_spike,
                        const float* __restrict__ tau_hist,
                        const float* __restrict__ K_hist,
                        const float* __restrict__ delta_hist,
                        float* __restrict__ Ct,
                        float* __restrict__ anc_kT,
                        float* __restrict__ hist_k,
                        int* __restrict__ flag) {
    const int tid = threadIdx.x;
    const int b   = blockIdx.x;
    if (b < 16) {
#pragma unroll
        for (int i = 0; i < 4; ++i) {
            const int q = b * 1024 + i * 256 + tid;   // q = s*128 + k
            Ct[(q & 127) * S_NO + (q >> 7)] = C[q];
        }
        return;
    }
    const int s    = tid & 127;
    const int half = tid >> 7;            // 0/1 -> j chunks of 52
    {   // ancestor kernel transposed, padded: anc_kT[j*128 + s], j in [0,104)
        float d  = delta_spike[s];
        float i0 = __expf(-tau_spike[0]);
        float i1 = __expf(-tau_spike[1]);
        float i2 = __expf(-tau_spike[2]);
        float k0 = K_spike[s * 3 + 0], k1 = K_spike[s * 3 + 1], k2 = K_spike[s * 3 + 2];
        for (int j = half * 52; j < half * 52 + 52; ++j) {
            float v = 0.0f;
            if (j < T_HIST) {
                float t  = fmaxf((float)j - d, 0.0f);
                float x0 = t * i0, x1 = t * i1, x2 = t * i2;
                v = k0 * x0 * __expf(-x0) + k1 * x1 * __expf(-x1) + k2 * x2 * __expf(-x2);
            }
            anc_kT[j * S_NO + s] = v;
        }
    }
    {   // history kernel per-subunit: hist_k[s*100 + j]
        float d  = delta_hist[s];
        float i0 = __expf(-tau_hist[0]);
        float i1 = __expf(-tau_hist[1]);
        float i2 = __expf(-tau_hist[2]);
        float k0 = K_hist[s * 3 + 0], k1 = K_hist[s * 3 + 1], k2 = K_hist[s * 3 + 2];
        for (int j = half * 50; j < half * 50 + 50; ++j) {
            float t  = fmaxf((float)j - d, 0.0f);
            float x0 = t * i0, x1 = t * i1, x2 = t * i2;
            hist_k[s * T_HIST + j] =
                k0 * x0 * __expf(-x0) + k1 * x1 * __expf(-x1) + k2 * x2 * __expf(-x2);
        }
    }
    if (tid == 0) *flag = 0;
    __syncthreads();
    if (tid < 128) {
        if (K_hist[s * 3] != 0.0f || K_hist[s * 3 + 1] != 0.0f || K_hist[s * 3 + 2] != 0.0f)
            atomicOr(flag, 1);
    }
}

// ---------------------------------------------------------------------------
// K2: dual GEMM  A = Z @ C^T (-> ws), R = Y @ C^T (-> out1)
// R3 version (best measured): block 32t x 128s, thread 4t x 4s for both
// outputs. Per k4-step: 4 global c-b128 (L1-hot) + 8 LDS b128 serve 128 FMA.
// ---------------------------------------------------------------------------
__global__ void __launch_bounds__(256) k2_gemm(const float* __restrict__ Z,
                                               const float* __restrict__ Y,
                                               const float* __restrict__ Ct,
                                               float* __restrict__ A,
                                               float* __restrict__ R) {
    __shared__ float Zt[32 * 128];
    __shared__ float Yt[32 * 128];
    const int t0  = blockIdx.x * 32;
    const int tid = threadIdx.x;
    {
        const float4* Zg = (const float4*)(Z + t0 * S_NO);
        const float4* Yg = (const float4*)(Y + t0 * S_NO);
        float4* Zl = (float4*)Zt;
        float4* Yl = (float4*)Yt;
        for (int q = tid; q < 1024; q += 256) { Zl[q] = Zg[q]; Yl[q] = Yg[q]; }
    }
    __syncthreads();
    const int sg = tid & 31;          // s0 = sg*4
    const int tg = tid >> 5;          // 0..7 -> local t = tg*4 + i
    const int s0 = sg * 4;
    float4 accA[4] = {{0,0,0,0},{0,0,0,0},{0,0,0,0},{0,0,0,0}};
    float4 accR[4] = {{0,0,0,0},{0,0,0,0},{0,0,0,0},{0,0,0,0}};
    for (int k4 = 0; k4 < 32; ++k4) {
        const float4 c0 = *(const float4*)&Ct[(k4 * 4 + 0) * S_NO + s0];
        const float4 c1 = *(const float4*)&Ct[(k4 * 4 + 1) * S_NO + s0];
        const float4 c2 = *(const float4*)&Ct[(k4 * 4 + 2) * S_NO + s0];
        const float4 c3 = *(const float4*)&Ct[(k4 * 4 + 3) * S_NO + s0];
#pragma unroll
        for (int i = 0; i < 4; ++i) {
            const float4 z = *(const float4*)&Zt[(tg * 4 + i) * S_NO + k4 * 4];
            fma4(accA[i], z.x, c0); fma4(accA[i], z.y, c1);
            fma4(accA[i], z.z, c2); fma4(accA[i], z.w, c3);
            const float4 y = *(const float4*)&Yt[(tg * 4 + i) * S_NO + k4 * 4];
            fma4(accR[i], y.x, c0); fma4(accR[i], y.y, c1);
            fma4(accR[i], y.z, c2); fma4(accR[i], y.w, c3);
        }
    }
#pragma unroll
    for (int i = 0; i < 4; ++i) {
        *(float4*)&A[(t0 + tg * 4 + i) * S_NO + s0] = accA[i];
        *(float4*)&R[(t0 + tg * 4 + i) * S_NO + s0] = accR[i];
    }
}

// ---------------------------------------------------------------------------
// K3: fused 100-tap causal conv + final map. No LDS, no barrier.
// Thread: one s, 8 t's; 13 chunks of 8 taps, 15-deep register window.
// __launch_bounds__(256,4) caps VGPR <= 128 (R4 defect: 248 VGPR);
// "#pragma unroll 1" on the chunk loop stops cross-chunk load hoisting.
// Logical grid 1250 slabs of 16 t; physical grid padded to 1256 = 8*157 so
// the XCD swizzle (b&7)*157+(b>>3) is a BIJECTION (R5 defect: 5 slabs
// unmapped). blk >= 1250 -> early return.
// ---------------------------------------------------------------------------
#define K3_LOGICAL 1250
#define K3_NPER    157                 // ceil(1250/8)
#define K3_PHYS    (8 * K3_NPER)       // 1256
template <bool GUARD>
__device__ __forceinline__ void conv8(const float* __restrict__ A,
                                      const float* __restrict__ kT,
                                      int t0, int s, float acc[8]) {
#pragma unroll 1
    for (int c = 0; c < 13; ++c) {
        const int B = t0 - 8 * c - 8;       // window base row
        float w[15];
        float kj[8];
#pragma unroll
        for (int q = 0; q < 15; ++q) {
            const int u = B + q;
            if (GUARD)
                w[q] = (u >= 0) ? A[u * S_NO + s] : 0.0f;
            else
                w[q] = A[u * S_NO + s];
        }
#pragma unroll
        for (int r = 0; r < 8; ++r) kj[r] = kT[(8 * c + r) * S_NO + s];
#pragma unroll
        for (int r = 0; r < 8; ++r)
#pragma unroll
            for (int i = 0; i < 8; ++i)
                acc[i] = fmaf(kj[r], w[i + 7 - r], acc[i]);   // row = t0+i-1-(8c+r)
    }
}

__global__ void __launch_bounds__(256, 4) k3_fused(const float* __restrict__ A,
                                                const float* __restrict__ anc_kT,
                                                const float* __restrict__ S_conv,
                                                const float* __restrict__ noise,
                                                const float* __restrict__ W_sub,
                                                const float* __restrict__ theta_syn,
                                                const float* __restrict__ theta_spike,
                                                const float* __restrict__ W_spike,
                                                const int* __restrict__ flag,
                                                float* __restrict__ out0,
                                                float* __restrict__ out1,
                                                float* __restrict__ out2,
                                                float* __restrict__ out3,
                                                float* __restrict__ Fws) {
    // bijective XCD swizzle over the padded grid [0, 1256)
    const int blk = (blockIdx.x & 7) * K3_NPER + (blockIdx.x >> 3);
    if (blk >= K3_LOGICAL) return;
    const int tid = threadIdx.x;
    const int s   = tid & 127;
    const int tg  = tid >> 7;                             // wave-uniform (0/1)
    const int t0  = blk * 16 + tg * 8;
    float acc[8] = {0,0,0,0,0,0,0,0};
    if (t0 >= J_PAD) conv8<false>(A, anc_kT, t0, s, acc);
    else             conv8<true >(A, anc_kT, t0, s, acc);

    if (*flag == 0) {
        const float tsy = theta_syn[s], wsub = W_sub[s];
        const float wsp = W_spike[s],  tsp  = theta_spike[s];
#pragma unroll
        for (int i = 0; i < 8; ++i) {
            const int n = (t0 + i) * S_NO + s;
            const float x  = sigm(S_conv[n] + tsy + out1[n] + acc[i]);
            const float dn = fmaf(x, wsp, tsp);
            const float z  = sigm(dn + noise[n]);
            out0[n] = x * wsub;
            out1[n] = z;
            out2[n] = dn;
            out3[n] = dn;
        }
    } else {
#pragma unroll
        for (int i = 0; i < 8; ++i) Fws[(t0 + i) * S_NO + s] = acc[i];
    }
}

// ---------------------------------------------------------------------------
// K4: exact sequential recurrence (only when hist kernel != 0).
// ---------------------------------------------------------------------------
__global__ void __launch_bounds__(64) k4_scan(const float* __restrict__ S_conv,
                                              const float* __restrict__ noise,
                                              const float* __restrict__ W_sub,
                                              const float* __restrict__ theta_syn,
                                              const float* __restrict__ theta_spike,
                                              const float* __restrict__ W_spike,
                                              const float* __restrict__ hist_k,
                                              const int* __restrict__ flag,
                                              const float* __restrict__ Fws,
                                              float* __restrict__ out0,
                                              float* __restrict__ out1,
                                              float* __restrict__ out2,
                                              float* __restrict__ out3) {
    if (*flag == 0) return;
    __shared__ float zr[128];
    const int s = blockIdx.x;
    const int l = threadIdx.x;
    zr[l] = 0.0f; zr[l + 64] = 0.0f;      // single wave: no barrier needed
    const float hk0 = (l < T_HIST) ? hist_k[s * T_HIST + l] : 0.0f;
    const float hk1 = (l + 64 < T_HIST) ? hist_k[s * T_HIST + l + 64] : 0.0f;
    const float tsy = theta_syn[s], wsub = W_sub[s];
    const float wsp = W_spike[s],  tsp  = theta_spike[s];
    for (int t = 0; t < T_DATA; ++t) {
        float fh = hk0 * zr[(t - 1 - l) & 127];
        fh = fmaf(hk1, zr[(t - 65 - l) & 127], fh);
#pragma unroll
        for (int m = 1; m < 64; m <<= 1) fh += __shfl_xor(fh, m, 64);
        const int n = t * S_NO + s;
        const float basev = S_conv[n] + tsy + out1[n] + Fws[n];
        const float x  = sigm(basev + fh);
        const float dn = fmaf(x, wsp, tsp);
        const float z  = sigm(dn + noise[n]);
        if (l == 0) {
            out0[n] = x * wsub;
            out1[n] = z;
            out2[n] = dn;
            out3[n] = dn;
            zr[t & 127] = z;
        }
    }
}

// ---------------------------------------------------------------------------
extern "C" void kernel_launch(void* const* d_in, const int* in_sizes, int n_in,
                              void* d_out, int out_size, void* d_ws, size_t ws_size,
                              hipStream_t stream) {
    const float* S_conv  = (const float*)d_in[0];
    const float* Y_anc   = (const float*)d_in[1];
    const float* Z_anc   = (const float*)d_in[2];
    const float* noise   = (const float*)d_in[3];
    const float* C_den   = (const float*)d_in[4];
    const float* W_sub   = (const float*)d_in[5];
    const float* th_syn  = (const float*)d_in[6];
    const float* K_spk   = (const float*)d_in[7];
    const float* tau_spk = (const float*)d_in[8];
    const float* dl_spk  = (const float*)d_in[9];
    const float* th_spk  = (const float*)d_in[10];
    const float* W_spk   = (const float*)d_in[11];
    const float* tau_h   = (const float*)d_in[12];
    const float* K_h     = (const float*)d_in[13];
    const float* dl_h    = (const float*)d_in[14];

    float* out  = (float*)d_out;
    float* out0 = out;
    float* out1 = out + NELEM;
    float* out2 = out + 2 * NELEM;
    float* out3 = out + 3 * NELEM;

    // workspace: A | F | Ct | anc_kT (104 rows) | hist_k | flag
    float* ws     = (float*)d_ws;
    float* wsA    = ws;
    float* wsF    = ws + NELEM;
    float* Ct     = ws + 2 * NELEM;
    float* anc_kT = Ct + S_NO * S_NO;
    float* hist_k = anc_kT + J_PAD * S_NO;
    int*   flag   = (int*)(hist_k + S_NO * T_HIST);

    k1_prep<<<17, 256, 0, stream>>>(C_den, K_spk, tau_spk, dl_spk, tau_h, K_h, dl_h,
                                    Ct, anc_kT, hist_k, flag);
    // A -> ws, R -> out1
    k2_gemm<<<T_DATA / 32, 256, 0, stream>>>(Z_anc, Y_anc, Ct, wsA, out1);
    // fused conv + final map (reads A from ws, R from out1)
    k3_fused<<<K3_PHYS, 256, 0, stream>>>(wsA, anc_kT, S_conv, noise,
                                          W_sub, th_syn, th_spk, W_spk,
                                          flag, out0, out1, out2, out3, wsF);
    // exact sequential path (no-op when hist kernel is all-zero)
    k4_scan<<<S_NO, 64, 0, stream>>>(S_conv, noise, W_sub, th_syn, th_spk, W_spk,
                                     hist_k, flag, wsF, out0, out1, out2, out3);
}

// Round 7
// 164.241 us; speedup vs baseline: 1.1735x; 1.0407x over previous
//
#include <hip/hip_runtime.h>

#define T_DATA 20000
#define S_NO   128
#define T_HIST 100
#define J_PAD  104              // conv taps padded to 13 chunks of 8 (zeros past 99)
#define NELEM  (T_DATA * S_NO)  // 2,560,000

__device__ __forceinline__ float sigm(float v) {
    return 1.0f / (1.0f + __expf(-v));
}

__device__ __forceinline__ void fma4(float4& a, float s, const float4 c) {
    a.x = fmaf(s, c.x, a.x); a.y = fmaf(s, c.y, a.y);
    a.z = fmaf(s, c.z, a.z); a.w = fmaf(s, c.w, a.w);
}

// ---------------------------------------------------------------------------
// K1: prep (17 blocks). blocks 0..15: transpose C -> Ct[k][s]
// block 16: ancestor kernel transposed [j][s] (padded to 104), history
// kernel [s][j], flag = any(K_hist != 0)
// ---------------------------------------------------------------------------
__global__ void __launch_bounds__(256) k1_prep(const float* __restrict__ C,
                        const float* __restrict__ K_spike,
                        const float* __restrict__ tau_spike,
                        const float* __restrict__ delta_spike,
                        const float* __restrict__ tau_hist,
                        const float* __restrict__ K_hist,
                        const float* __restrict__ delta_hist,
                        float* __restrict__ Ct,
                        float* __restrict__ anc_kT,
                        float* __restrict__ hist_k,
                        int* __restrict__ flag) {
    const int tid = threadIdx.x;
    const int b   = blockIdx.x;
    if (b < 16) {
#pragma unroll
        for (int i = 0; i < 4; ++i) {
            const int q = b * 1024 + i * 256 + tid;   // q = s*128 + k
            Ct[(q & 127) * S_NO + (q >> 7)] = C[q];
        }
        return;
    }
    const int s    = tid & 127;
    const int half = tid >> 7;
    {   // ancestor kernel transposed, padded: anc_kT[j*128 + s], j in [0,104)
        float d  = delta_spike[s];
        float i0 = __expf(-tau_spike[0]);
        float i1 = __expf(-tau_spike[1]);
        float i2 = __expf(-tau_spike[2]);
        float k0 = K_spike[s * 3 + 0], k1 = K_spike[s * 3 + 1], k2 = K_spike[s * 3 + 2];
        for (int j = half * 52; j < half * 52 + 52; ++j) {
            float v = 0.0f;
            if (j < T_HIST) {
                float t  = fmaxf((float)j - d, 0.0f);
                float x0 = t * i0, x1 = t * i1, x2 = t * i2;
                v = k0 * x0 * __expf(-x0) + k1 * x1 * __expf(-x1) + k2 * x2 * __expf(-x2);
            }
            anc_kT[j * S_NO + s] = v;
        }
    }
    {   // history kernel per-subunit: hist_k[s*100 + j]
        float d  = delta_hist[s];
        float i0 = __expf(-tau_hist[0]);
        float i1 = __expf(-tau_hist[1]);
        float i2 = __expf(-tau_hist[2]);
        float k0 = K_hist[s * 3 + 0], k1 = K_hist[s * 3 + 1], k2 = K_hist[s * 3 + 2];
        for (int j = half * 50; j < half * 50 + 50; ++j) {
            float t  = fmaxf((float)j - d, 0.0f);
            float x0 = t * i0, x1 = t * i1, x2 = t * i2;
            hist_k[s * T_HIST + j] =
                k0 * x0 * __expf(-x0) + k1 * x1 * __expf(-x1) + k2 * x2 * __expf(-x2);
        }
    }
    if (tid == 0) *flag = 0;
    __syncthreads();
    if (tid < 128) {
        if (K_hist[s * 3] != 0.0f || K_hist[s * 3 + 1] != 0.0f || K_hist[s * 3 + 2] != 0.0f)
            atomicOr(flag, 1);
    }
}

// ---------------------------------------------------------------------------
// K2: dual GEMM  A = Z @ C^T (-> ws), R = Y @ C^T (-> out1)
// R3/R6 version (known-good): block 32t x 128s, thread 4t x 4s.
// ---------------------------------------------------------------------------
__global__ void __launch_bounds__(256) k2_gemm(const float* __restrict__ Z,
                                               const float* __restrict__ Y,
                                               const float* __restrict__ Ct,
                                               float* __restrict__ A,
                                               float* __restrict__ R) {
    __shared__ float Zt[32 * 128];
    __shared__ float Yt[32 * 128];
    const int t0  = blockIdx.x * 32;
    const int tid = threadIdx.x;
    {
        const float4* Zg = (const float4*)(Z + t0 * S_NO);
        const float4* Yg = (const float4*)(Y + t0 * S_NO);
        float4* Zl = (float4*)Zt;
        float4* Yl = (float4*)Yt;
        for (int q = tid; q < 1024; q += 256) { Zl[q] = Zg[q]; Yl[q] = Yg[q]; }
    }
    __syncthreads();
    const int sg = tid & 31;          // s0 = sg*4
    const int tg = tid >> 5;          // 0..7 -> local t = tg*4 + i
    const int s0 = sg * 4;
    float4 accA[4] = {{0,0,0,0},{0,0,0,0},{0,0,0,0},{0,0,0,0}};
    float4 accR[4] = {{0,0,0,0},{0,0,0,0},{0,0,0,0},{0,0,0,0}};
    for (int k4 = 0; k4 < 32; ++k4) {
        const float4 c0 = *(const float4*)&Ct[(k4 * 4 + 0) * S_NO + s0];
        const float4 c1 = *(const float4*)&Ct[(k4 * 4 + 1) * S_NO + s0];
        const float4 c2 = *(const float4*)&Ct[(k4 * 4 + 2) * S_NO + s0];
        const float4 c3 = *(const float4*)&Ct[(k4 * 4 + 3) * S_NO + s0];
#pragma unroll
        for (int i = 0; i < 4; ++i) {
            const float4 z = *(const float4*)&Zt[(tg * 4 + i) * S_NO + k4 * 4];
            fma4(accA[i], z.x, c0); fma4(accA[i], z.y, c1);
            fma4(accA[i], z.z, c2); fma4(accA[i], z.w, c3);
            const float4 y = *(const float4*)&Yt[(tg * 4 + i) * S_NO + k4 * 4];
            fma4(accR[i], y.x, c0); fma4(accR[i], y.y, c1);
            fma4(accR[i], y.z, c2); fma4(accR[i], y.w, c3);
        }
    }
#pragma unroll
    for (int i = 0; i < 4; ++i) {
        *(float4*)&A[(t0 + tg * 4 + i) * S_NO + s0] = accA[i];
        *(float4*)&R[(t0 + tg * 4 + i) * S_NO + s0] = accR[i];
    }
}

// ---------------------------------------------------------------------------
// K3: fused 100-tap conv + final map. Gather-from-global, no LDS/barrier.
// Thread: one s, 8 t's; 13 chunks of 8 taps. NEW vs R6: explicit
// double-buffered chunk pipeline (load chunk c+1 while FMA-ing chunk c,
// loop unrolled x2 so buffer indices stay static) -> memory pipe stays
// busy instead of the R6 load-wait-compute serialization. Cold final-map
// streams (S_conv, noise) prefetched before the conv to hide HBM latency.
// ---------------------------------------------------------------------------
#define K3_LOGICAL 1250
#define K3_NPER    157                 // ceil(1250/8)
#define K3_PHYS    (8 * K3_NPER)       // 1256

__device__ __forceinline__ void k3_load_chunk(const float* __restrict__ A,
                                              const float* __restrict__ kT,
                                              int t0, int s, int c,
                                              float w[15], float kj[8]) {
    const int B = t0 - 8 * c - 8;
#pragma unroll
    for (int q = 0; q < 15; ++q) w[q] = A[(B + q) * S_NO + s];
#pragma unroll
    for (int r = 0; r < 8; ++r) kj[r] = kT[(8 * c + r) * S_NO + s];
}

__device__ __forceinline__ void k3_fma_chunk(const float w[15], const float kj[8],
                                             float acc[8]) {
#pragma unroll
    for (int r = 0; r < 8; ++r)
#pragma unroll
        for (int i = 0; i < 8; ++i)
            acc[i] = fmaf(kj[r], w[i + 7 - r], acc[i]);   // row = t0+i-1-(8c+r)
}

// guarded (t0 < 104) fallback: serial, with u>=0 checks — 7 blocks only
__device__ __forceinline__ void conv8_guard(const float* __restrict__ A,
                                            const float* __restrict__ kT,
                                            int t0, int s, float acc[8]) {
#pragma unroll 1
    for (int c = 0; c < 13; ++c) {
        const int B = t0 - 8 * c - 8;
        float w[15], kj[8];
#pragma unroll
        for (int q = 0; q < 15; ++q) {
            const int u = B + q;
            w[q] = (u >= 0) ? A[u * S_NO + s] : 0.0f;
        }
#pragma unroll
        for (int r = 0; r < 8; ++r) kj[r] = kT[(8 * c + r) * S_NO + s];
        k3_fma_chunk(w, kj, acc);
    }
}

__global__ void __launch_bounds__(256, 4) k3_fused(const float* __restrict__ A,
                                                const float* __restrict__ anc_kT,
                                                const float* __restrict__ S_conv,
                                                const float* __restrict__ noise,
                                                const float* __restrict__ W_sub,
                                                const float* __restrict__ theta_syn,
                                                const float* __restrict__ theta_spike,
                                                const float* __restrict__ W_spike,
                                                const int* __restrict__ flag,
                                                float* __restrict__ out0,
                                                float* __restrict__ out1,
                                                float* __restrict__ out2,
                                                float* __restrict__ out3,
                                                float* __restrict__ Fws) {
    // bijective XCD swizzle over the padded grid [0, 1256)
    const int blk = (blockIdx.x & 7) * K3_NPER + (blockIdx.x >> 3);
    if (blk >= K3_LOGICAL) return;
    const int tid = threadIdx.x;
    const int s   = tid & 127;
    const int tg  = tid >> 7;                             // wave-uniform (0/1)
    const int t0  = blk * 16 + tg * 8;
    const int fl  = *flag;

    // prefetch the two HBM-cold final-map streams; latency hides under conv
    float sc[8], nz[8];
#pragma unroll
    for (int i = 0; i < 8; ++i) {
        const int n = (t0 + i) * S_NO + s;
        sc[i] = S_conv[n];
        nz[i] = noise[n];
    }

    float acc[8] = {0,0,0,0,0,0,0,0};
    if (t0 >= J_PAD) {
        // software-pipelined: double-buffered window/taps, rolled x2 loop
        float w0[15], k0[8], w1[15], k1[8];
        k3_load_chunk(A, anc_kT, t0, s, 0, w0, k0);
#pragma unroll 1
        for (int c = 0; c < 12; c += 2) {
            k3_load_chunk(A, anc_kT, t0, s, c + 1, w1, k1);
            k3_fma_chunk(w0, k0, acc);
            k3_load_chunk(A, anc_kT, t0, s, c + 2, w0, k0);
            k3_fma_chunk(w1, k1, acc);
        }
        k3_fma_chunk(w0, k0, acc);                        // chunk 12
    } else {
        conv8_guard(A, anc_kT, t0, s, acc);
    }

    if (fl == 0) {
        const float tsy = theta_syn[s], wsub = W_sub[s];
        const float wsp = W_spike[s],  tsp  = theta_spike[s];
#pragma unroll
        for (int i = 0; i < 8; ++i) {
            const int n = (t0 + i) * S_NO + s;
            const float x  = sigm(sc[i] + tsy + out1[n] + acc[i]);
            const float dn = fmaf(x, wsp, tsp);
            const float z  = sigm(dn + nz[i]);
            out0[n] = x * wsub;
            out1[n] = z;
            out2[n] = dn;
            out3[n] = dn;
        }
    } else {
#pragma unroll
        for (int i = 0; i < 8; ++i) Fws[(t0 + i) * S_NO + s] = acc[i];
    }
}

// ---------------------------------------------------------------------------
// K4: exact sequential recurrence (only when hist kernel != 0).
// ---------------------------------------------------------------------------
__global__ void __launch_bounds__(64) k4_scan(const float* __restrict__ S_conv,
                                              const float* __restrict__ noise,
                                              const float* __restrict__ W_sub,
                                              const float* __restrict__ theta_syn,
                                              const float* __restrict__ theta_spike,
                                              const float* __restrict__ W_spike,
                                              const float* __restrict__ hist_k,
                                              const int* __restrict__ flag,
                                              const float* __restrict__ Fws,
                                              float* __restrict__ out0,
                                              float* __restrict__ out1,
                                              float* __restrict__ out2,
                                              float* __restrict__ out3) {
    if (*flag == 0) return;
    __shared__ float zr[128];
    const int s = blockIdx.x;
    const int l = threadIdx.x;
    zr[l] = 0.0f; zr[l + 64] = 0.0f;      // single wave: no barrier needed
    const float hk0 = (l < T_HIST) ? hist_k[s * T_HIST + l] : 0.0f;
    const float hk1 = (l + 64 < T_HIST) ? hist_k[s * T_HIST + l + 64] : 0.0f;
    const float tsy = theta_syn[s], wsub = W_sub[s];
    const float wsp = W_spike[s],  tsp  = theta_spike[s];
    for (int t = 0; t < T_DATA; ++t) {
        float fh = hk0 * zr[(t - 1 - l) & 127];
        fh = fmaf(hk1, zr[(t - 65 - l) & 127], fh);
#pragma unroll
        for (int m = 1; m < 64; m <<= 1) fh += __shfl_xor(fh, m, 64);
        const int n = t * S_NO + s;
        const float basev = S_conv[n] + tsy + out1[n] + Fws[n];
        const float x  = sigm(basev + fh);
        const float dn = fmaf(x, wsp, tsp);
        const float z  = sigm(dn + noise[n]);
        if (l == 0) {
            out0[n] = x * wsub;
            out1[n] = z;
            out2[n] = dn;
            out3[n] = dn;
            zr[t & 127] = z;
        }
    }
}

// ---------------------------------------------------------------------------
extern "C" void kernel_launch(void* const* d_in, const int* in_sizes, int n_in,
                              void* d_out, int out_size, void* d_ws, size_t ws_size,
                              hipStream_t stream) {
    const float* S_conv  = (const float*)d_in[0];
    const float* Y_anc   = (const float*)d_in[1];
    const float* Z_anc   = (const float*)d_in[2];
    const float* noise   = (const float*)d_in[3];
    const float* C_den   = (const float*)d_in[4];
    const float* W_sub   = (const float*)d_in[5];
    const float* th_syn  = (const float*)d_in[6];
    const float* K_spk   = (const float*)d_in[7];
    const float* tau_spk = (const float*)d_in[8];
    const float* dl_spk  = (const float*)d_in[9];
    const float* th_spk  = (const float*)d_in[10];
    const float* W_spk   = (const float*)d_in[11];
    const float* tau_h   = (const float*)d_in[12];
    const float* K_h     = (const float*)d_in[13];
    const float* dl_h    = (const float*)d_in[14];

    float* out  = (float*)d_out;
    float* out0 = out;
    float* out1 = out + NELEM;
    float* out2 = out + 2 * NELEM;
    float* out3 = out + 3 * NELEM;

    // workspace: A | F | Ct | anc_kT (104 rows) | hist_k | flag
    float* ws     = (float*)d_ws;
    float* wsA    = ws;
    float* wsF    = ws + NELEM;
    float* Ct     = ws + 2 * NELEM;
    float* anc_kT = Ct + S_NO * S_NO;
    float* hist_k = anc_kT + J_PAD * S_NO;
    int*   flag   = (int*)(hist_k + S_NO * T_HIST);

    k1_prep<<<17, 256, 0, stream>>>(C_den, K_spk, tau_spk, dl_spk, tau_h, K_h, dl_h,
                                    Ct, anc_kT, hist_k, flag);
    // A -> ws, R -> out1
    k2_gemm<<<T_DATA / 32, 256, 0, stream>>>(Z_anc, Y_anc, Ct, wsA, out1);
    // fused conv + final map (reads A from ws, R from out1)
    k3_fused<<<K3_PHYS, 256, 0, stream>>>(wsA, anc_kT, S_conv, noise,
                                          W_sub, th_syn, th_spk, W_spk,
                                          flag, out0, out1, out2, out3, wsF);
    // exact sequential path (no-op when hist kernel is all-zero)
    k4_scan<<<S_NO, 64, 0, stream>>>(S_conv, noise, W_sub, th_syn, th_spk, W_spk,
                                     hist_k, flag, wsF, out0, out1, out2, out3);
}